// Round 3
// baseline (119.520 us; speedup 1.0000x reference)
//
#include <hip/hip_runtime.h>
#include <hip/hip_bf16.h>

#define BB 64
#define NN 96
#define FF 16
#define HH 128
#define KK 64
#define LL 3
#define CUTOFF_F 10.0f
#define GAMMA_F 10.0f

#define W2_BLOCKS 98          // ceil(3*65*128 / 256)
#define CNT_BLOCKS BB
#define S_BLOCKS (BB * NN / 4)

// ---------------------------------------------------------------------------
// pre_kernel (heterogeneous):
//   [0,98):   W2[l] = Wrbf[l]@Wpair[l], c2[l] = brbf[l]@Wpair[l]+bpair[l]
//   [98,162): cnt[b] = #valid atoms; also zero out[b] (atomic target in chain)
//   [162,..): S[b,j,k] = sum_{i valid} exp(-g*(d(i,j)-c_k)^2), 4 j per block,
//             R + validity staged in LDS; invalid-j waves write a zero row.
// ---------------------------------------------------------------------------
__global__ __launch_bounds__(256) void pre_kernel(
    const float* __restrict__ Wrbf, const float* __restrict__ brbf,
    const float* __restrict__ Wpair, const float* __restrict__ bpair,
    const int* __restrict__ batch, const float* __restrict__ R,
    float* __restrict__ W2, float* __restrict__ c2,
    float* __restrict__ cnt, float* __restrict__ S,
    float* __restrict__ out)
{
    const int bid = blockIdx.x;
    const int tid = threadIdx.x;
    if (bid < W2_BLOCKS) {
        int idx = bid * 256 + tid;
        const int total = LL * (KK + 1) * HH;
        if (idx >= total) return;
        int h  = idx % HH;
        int kk = (idx / HH) % (KK + 1);
        int l  = idx / (HH * (KK + 1));
        const float* Wp = Wpair + l * HH * HH;
        if (kk < KK) {
            const float* wr = Wrbf + (l * KK + kk) * HH;
            float acc = 0.f;
            #pragma unroll 8
            for (int m = 0; m < HH; ++m) acc += wr[m] * Wp[m * HH + h];
            W2[(l * KK + kk) * HH + h] = acc;
        } else {
            const float* br = brbf + l * HH;
            float acc = bpair[l * HH + h];
            #pragma unroll 8
            for (int m = 0; m < HH; ++m) acc += br[m] * Wp[m * HH + h];
            c2[l * HH + h] = acc;
        }
    } else if (bid < W2_BLOCKS + CNT_BLOCKS) {
        int b = bid - W2_BLOCKS;
        __shared__ int c[4];
        bool v = (tid < NN) && (batch[b * NN + tid] != -1);
        unsigned long long m = __ballot(v);
        if ((tid & 63) == 0) c[tid >> 6] = __popcll(m);
        __syncthreads();
        if (tid == 0) {
            cnt[b] = (float)(c[0] + c[1] + c[2] + c[3]);
            out[b] = 0.f;                 // zero the atomic target each call
        }
    } else {
        __shared__ float sRf[NN * 3];
        __shared__ int   sBt[NN];
        int g  = bid - W2_BLOCKS - CNT_BLOCKS;
        int b  = g / (NN / 4);
        int j  = (g % (NN / 4)) * 4 + (tid >> 6);
        int k  = tid & 63;
        for (int t = tid; t < NN * 3; t += 256) sRf[t] = R[b * NN * 3 + t];
        for (int t = tid; t < NN; t += 256) sBt[t] = batch[b * NN + t];
        __syncthreads();
        float* Srow = S + (b * NN + j) * KK;
        if (sBt[j] == -1) { Srow[k] = 0.f; return; }   // wave-uniform
        const float xj = sRf[j * 3 + 0];
        const float yj = sRf[j * 3 + 1];
        const float zj = sRf[j * 3 + 2];
        const float ck = (float)k * (CUTOFF_F / (float)(KK - 1));
        float acc = 0.f;
        for (int i = 0; i < NN; ++i) {
            if (sBt[i] == -1) continue;                // wave-uniform
            float dx = sRf[i * 3 + 0] - xj;
            float dy = sRf[i * 3 + 1] - yj;
            float dz = sRf[i * 3 + 2] - zj;
            float d  = sqrtf(dx * dx + dy * dy + dz * dz);
            float u  = d - ck;
            acc += __expf(-GAMMA_F * u * u);
        }
        Srow[k] = acc;
    }
}

// ---------------------------------------------------------------------------
// w3_kernel: W3[l] = W2[l] @ Wa1[l]; c3[l] = c2[l] @ Wa1[l]
// ---------------------------------------------------------------------------
__global__ __launch_bounds__(256) void w3_kernel(
    const float* __restrict__ W2, const float* __restrict__ c2,
    const float* __restrict__ Wa1,
    float* __restrict__ W3, float* __restrict__ c3)
{
    int idx = blockIdx.x * 256 + threadIdx.x;
    const int total = LL * (KK + 1) * HH;
    if (idx >= total) return;
    int h  = idx % HH;
    int kk = (idx / HH) % (KK + 1);
    int l  = idx / (HH * (KK + 1));
    const float* Wa = Wa1 + l * HH * HH;
    if (kk < KK) {
        const float* row = W2 + (l * KK + kk) * HH;
        float acc = 0.f;
        #pragma unroll 8
        for (int m = 0; m < HH; ++m) acc += row[m] * Wa[m * HH + h];
        W3[(l * KK + kk) * HH + h] = acc;
    } else {
        const float* row = c2 + l * HH;
        float acc = 0.f;
        #pragma unroll 8
        for (int m = 0; m < HH; ++m) acc += row[m] * Wa[m * HH + h];
        c3[l * HH + h] = acc;
    }
}

// ---------------------------------------------------------------------------
// chain_kernel: per-atom MLP chain, register-tiled.
// Block = 256 threads = 128 channels x 2 atom-groups of 4 atoms (AT=8).
//   h = X@We + be
//   per l: t = silu(S@W3[l] + cnt*c3[l] + ba1[l]); h += t@Wa2[l] + ba2[l]
//   block-partial sum of valid silu(h@Wo1+bo1)@Wo2+bo2 -> atomicAdd(out[b], /cnt)
// ---------------------------------------------------------------------------
#define AT 8
#define ATP 12   // padded row: 48B -> float4-aligned slots

__global__ __launch_bounds__(256) void chain_kernel(
    const float* __restrict__ X, const int* __restrict__ batch,
    const float* __restrict__ We, const float* __restrict__ be,
    const float* __restrict__ ba1,
    const float* __restrict__ Wa2, const float* __restrict__ ba2,
    const float* __restrict__ Wo1, const float* __restrict__ bo1,
    const float* __restrict__ Wo2, const float* __restrict__ bo2,
    const float* __restrict__ S, const float* __restrict__ W3,
    const float* __restrict__ c3, const float* __restrict__ cnt,
    float* __restrict__ out)
{
    __shared__ __align__(16) float sS[KK][ATP];
    __shared__ __align__(16) float tb[HH][ATP];
    __shared__ __align__(16) float sX[FF][ATP];
    __shared__ float pr[4][4];
    __shared__ float po[AT];
    __shared__ float svalid[AT];

    const int tid = threadIdx.x;
    const int hh  = tid & 127;
    const int sh  = tid >> 7;            // atom group: atoms sh*4 .. sh*4+3
    const int a0  = blockIdx.x * AT;     // 96 % 8 == 0 -> block within one molecule
    const int b   = a0 / NN;
    const float cb = cnt[b];

    // ---- stage S^T, X^T, validity ----
    {
        int k = tid & 63, al = tid >> 6;
        sS[k][al]     = S[(a0 + al) * KK + k];
        sS[k][al + 4] = S[(a0 + al + 4) * KK + k];
    }
    {
        int f = tid & 15, al = tid >> 4;
        if (al < AT) sX[f][al] = X[(a0 + al) * FF + f];
    }
    if (tid < AT) svalid[tid] = (batch[a0 + tid] != -1) ? 1.f : 0.f;
    __syncthreads();

    // ---- embedding: h = X@We + be ----
    float h[4];
    {
        float acc[4] = {0, 0, 0, 0};
        const float* wp = We + hh;
        #pragma unroll
        for (int f = 0; f < FF; ++f) {
            float w = wp[f * HH];
            float4 u = *(const float4*)&sX[f][sh * 4];
            acc[0] += w * u.x; acc[1] += w * u.y; acc[2] += w * u.z; acc[3] += w * u.w;
        }
        float bee = be[hh];
        #pragma unroll
        for (int a = 0; a < 4; ++a) h[a] = acc[a] + bee;
    }

    // ---- layers ----
    for (int l = 0; l < LL; ++l) {
        float acc[4] = {0, 0, 0, 0};
        const float* wp = W3 + l * KK * HH + hh;
        #pragma unroll 8
        for (int k = 0; k < KK; ++k) {
            float w = wp[k * HH];
            float4 u = *(const float4*)&sS[k][sh * 4];
            acc[0] += w * u.x; acc[1] += w * u.y; acc[2] += w * u.z; acc[3] += w * u.w;
        }
        float bias = cb * c3[l * HH + hh] + ba1[l * HH + hh];

        __syncthreads();   // previous consumers of tb done
        {
            float4 t0; float v;
            v = acc[0] + bias; t0.x = v / (1.f + __expf(-v));
            v = acc[1] + bias; t0.y = v / (1.f + __expf(-v));
            v = acc[2] + bias; t0.z = v / (1.f + __expf(-v));
            v = acc[3] + bias; t0.w = v / (1.f + __expf(-v));
            *(float4*)&tb[hh][sh * 4] = t0;
        }
        __syncthreads();

        float acc2[4] = {0, 0, 0, 0};
        const float* wq = Wa2 + l * HH * HH + hh;
        #pragma unroll 8
        for (int m = 0; m < HH; ++m) {
            float w = wq[m * HH];
            float4 u = *(const float4*)&tb[m][sh * 4];
            acc2[0] += w * u.x; acc2[1] += w * u.y; acc2[2] += w * u.z; acc2[3] += w * u.w;
        }
        float b2 = ba2[l * HH + hh];
        #pragma unroll
        for (int a = 0; a < 4; ++a) h[a] += acc2[a] + b2;
    }

    // ---- output head ----
    __syncthreads();
    *(float4*)&tb[hh][sh * 4] = make_float4(h[0], h[1], h[2], h[3]);
    __syncthreads();

    float acc[4] = {0, 0, 0, 0};
    const float* wp = Wo1 + hh;
    #pragma unroll 8
    for (int m = 0; m < HH; ++m) {
        float w = wp[m * HH];
        float4 u = *(const float4*)&tb[m][sh * 4];
        acc[0] += w * u.x; acc[1] += w * u.y; acc[2] += w * u.z; acc[3] += w * u.w;
    }
    float bo = bo1[hh], wo2 = Wo2[hh];
    float contrib[4];
    #pragma unroll
    for (int a = 0; a < 4; ++a) {
        float v = acc[a] + bo;
        contrib[a] = (v / (1.f + __expf(-v))) * wo2;
    }
    #pragma unroll
    for (int a = 0; a < 4; ++a) {
        float r = contrib[a];
        for (int off = 32; off > 0; off >>= 1) r += __shfl_down(r, off);
        contrib[a] = r;
    }
    if ((tid & 63) == 0) {
        int w = tid >> 6;
        #pragma unroll
        for (int a = 0; a < 4; ++a) pr[w][a] = contrib[a];
    }
    __syncthreads();
    if (tid < AT) {
        int shh = tid >> 2, ai = tid & 3;
        float o = pr[2 * shh][ai] + pr[2 * shh + 1][ai] + bo2[0];
        po[tid] = (svalid[tid] != 0.f) ? o : 0.f;   // select: kills any NaN path
    }
    __syncthreads();
    if (tid == 0) {
        float s = 0.f;
        #pragma unroll
        for (int i = 0; i < AT; ++i) s += po[i];
        atomicAdd(out + b, s / cb);
    }
}

extern "C" void kernel_launch(void* const* d_in, const int* in_sizes, int n_in,
                              void* d_out, int out_size, void* d_ws, size_t ws_size,
                              hipStream_t stream) {
    const float* X     = (const float*)d_in[0];
    const float* R     = (const float*)d_in[1];
    const int*   batch = (const int*)  d_in[2];
    const float* We    = (const float*)d_in[3];
    const float* be    = (const float*)d_in[4];
    const float* Wrbf  = (const float*)d_in[5];
    const float* brbf  = (const float*)d_in[6];
    const float* Wpair = (const float*)d_in[7];
    const float* bpair = (const float*)d_in[8];
    const float* Wa1   = (const float*)d_in[9];
    const float* ba1   = (const float*)d_in[10];
    const float* Wa2   = (const float*)d_in[11];
    const float* ba2   = (const float*)d_in[12];
    const float* Wo1   = (const float*)d_in[13];
    const float* bo1   = (const float*)d_in[14];
    const float* Wo2   = (const float*)d_in[15];
    const float* bo2   = (const float*)d_in[16];

    float* w   = (float*)d_ws;
    float* S   = w;                        // B*N*K = 393216
    float* W2  = S  + BB * NN * KK;        // L*K*H = 24576
    float* c2  = W2 + LL * KK * HH;        // L*H   = 384
    float* W3  = c2 + LL * HH;             // L*K*H = 24576
    float* c3  = W3 + LL * KK * HH;        // L*H   = 384
    float* cnt = c3 + LL * HH;             // B     = 64
    float* out = (float*)d_out;

    hipLaunchKernelGGL(pre_kernel, dim3(W2_BLOCKS + CNT_BLOCKS + S_BLOCKS), dim3(256),
                       0, stream, Wrbf, brbf, Wpair, bpair, batch, R, W2, c2, cnt, S, out);
    hipLaunchKernelGGL(w3_kernel, dim3(W2_BLOCKS), dim3(256), 0, stream,
                       W2, c2, Wa1, W3, c3);
    hipLaunchKernelGGL(chain_kernel, dim3(BB * NN / AT), dim3(256), 0, stream,
                       X, batch, We, be, ba1, Wa2, ba2, Wo1, bo1, Wo2, bo2,
                       S, W3, c3, cnt, out);
}

// Round 4
// 66.596 us; speedup vs baseline: 1.7947x; 1.7947x over previous
//
#include <hip/hip_runtime.h>
#include <hip/hip_bf16.h>

#define BB 64
#define NN 96
#define FF 16
#define HH 128
#define KK 64
#define LL 3
#define CUTOFF_F 10.0f
#define GAMMA_F 10.0f

#define WT_BLOCKS 99          // 3 layers * 33 blocks (2 rows of W2/W3 each, 65 rows/layer)
#define CNT_BLOCKS BB
#define S_BLOCKS (BB * NN / 4)

// ---------------------------------------------------------------------------
// pre_kernel (heterogeneous):
//   [0,99):   weights: rows {2i,2i+1} of W2[l]=Wrbf@Wpair (row 64 = bias row c2),
//             staged in LDS, then W3 rows = W2row@Wa1 (row 64 -> c3). W2 never
//             hits global.
//   [99,163): cnt[b] = #valid atoms; zero out[b] (atomic target in chain)
//   [163,..): S[b,j,k] = sum_{i valid} exp(-g*(d(i,j)-c_k)^2), 4 j per block,
//             R + validity staged in LDS; invalid-j waves write a zero row.
// ---------------------------------------------------------------------------
__global__ __launch_bounds__(256) void pre_kernel(
    const float* __restrict__ Wrbf, const float* __restrict__ brbf,
    const float* __restrict__ Wpair, const float* __restrict__ bpair,
    const float* __restrict__ Wa1,
    const int* __restrict__ batch, const float* __restrict__ R,
    float* __restrict__ W3, float* __restrict__ c3,
    float* __restrict__ cnt, float* __restrict__ S,
    float* __restrict__ out)
{
    const int bid = blockIdx.x;
    const int tid = threadIdx.x;
    if (bid < WT_BLOCKS) {
        __shared__ float sW2[2][HH];
        const int l    = bid / 33;
        const int r0   = (bid % 33) * 2;
        const int half = tid >> 7;
        const int h    = tid & 127;
        const int kk   = r0 + half;       // 0..65 (65 inactive)
        const bool active = (kk <= KK);
        if (active) {
            const float* Wp = Wpair + l * HH * HH + h;
            const float* arow;
            float acc;
            if (kk < KK) { arow = Wrbf + (l * KK + kk) * HH; acc = 0.f; }
            else         { arow = brbf + l * HH;             acc = bpair[l * HH + h]; }
            #pragma unroll 8
            for (int m = 0; m < HH; ++m) acc += arow[m] * Wp[m * HH];
            sW2[half][h] = acc;
        }
        __syncthreads();
        if (active) {
            const float* Wa = Wa1 + l * HH * HH + h;
            const float* row = sW2[half];
            float a3 = 0.f;
            #pragma unroll 8
            for (int m = 0; m < HH; ++m) a3 += row[m] * Wa[m * HH];
            if (kk < KK) W3[(l * KK + kk) * HH + h] = a3;
            else         c3[l * HH + h] = a3;
        }
    } else if (bid < WT_BLOCKS + CNT_BLOCKS) {
        int b = bid - WT_BLOCKS;
        __shared__ int c[4];
        bool v = (tid < NN) && (batch[b * NN + tid] != -1);
        unsigned long long m = __ballot(v);
        if ((tid & 63) == 0) c[tid >> 6] = __popcll(m);
        __syncthreads();
        if (tid == 0) {
            cnt[b] = (float)(c[0] + c[1] + c[2] + c[3]);
            out[b] = 0.f;                 // zero the atomic target each call
        }
    } else {
        __shared__ float sRf[NN * 3];
        __shared__ int   sBt[NN];
        int g  = bid - WT_BLOCKS - CNT_BLOCKS;
        int b  = g / (NN / 4);
        int j  = (g % (NN / 4)) * 4 + (tid >> 6);
        int k  = tid & 63;
        for (int t = tid; t < NN * 3; t += 256) sRf[t] = R[b * NN * 3 + t];
        for (int t = tid; t < NN; t += 256) sBt[t] = batch[b * NN + t];
        __syncthreads();
        float* Srow = S + (b * NN + j) * KK;
        if (sBt[j] == -1) { Srow[k] = 0.f; return; }   // wave-uniform
        const float xj = sRf[j * 3 + 0];
        const float yj = sRf[j * 3 + 1];
        const float zj = sRf[j * 3 + 2];
        const float ck = (float)k * (CUTOFF_F / (float)(KK - 1));
        float acc = 0.f;
        for (int i = 0; i < NN; ++i) {
            if (sBt[i] == -1) continue;                // wave-uniform
            float dx = sRf[i * 3 + 0] - xj;
            float dy = sRf[i * 3 + 1] - yj;
            float dz = sRf[i * 3 + 2] - zj;
            float d  = sqrtf(dx * dx + dy * dy + dz * dz);
            float u  = d - ck;
            acc += __expf(-GAMMA_F * u * u);
        }
        Srow[k] = acc;
    }
}

// ---------------------------------------------------------------------------
// chain_kernel: per-atom MLP chain, register-tiled with explicit 2-stage
// weight prefetch (software pipeline) in every inner GEMM loop.
// Block = 256 threads = 128 channels x 2 atom-halves of 8 atoms (AT=16).
//   h = X@We + be
//   per l: t = silu(S@W3[l] + cnt*c3[l] + ba1[l]); h += t@Wa2[l] + ba2[l]
//   block-partial of valid silu(h@Wo1+bo1)@Wo2+bo2 -> atomicAdd(out[b], /cnt)
// ---------------------------------------------------------------------------
#define AT 16
#define ATP (AT + 4)   // padded row: 20 floats

// FMA over 8 atoms with one weight scalar from register
#define FMA8(ACC, W, ROWPTR)                                             \
    do {                                                                 \
        float4 _u0 = *(const float4*)&(ROWPTR)[sh * 8];                  \
        float4 _u1 = *(const float4*)&(ROWPTR)[sh * 8 + 4];              \
        ACC[0] += (W) * _u0.x; ACC[1] += (W) * _u0.y;                    \
        ACC[2] += (W) * _u0.z; ACC[3] += (W) * _u0.w;                    \
        ACC[4] += (W) * _u1.x; ACC[5] += (W) * _u1.y;                    \
        ACC[6] += (W) * _u1.z; ACC[7] += (W) * _u1.w;                    \
    } while (0)

__global__ __launch_bounds__(256) void chain_kernel(
    const float* __restrict__ X, const int* __restrict__ batch,
    const float* __restrict__ We, const float* __restrict__ be,
    const float* __restrict__ ba1,
    const float* __restrict__ Wa2, const float* __restrict__ ba2,
    const float* __restrict__ Wo1, const float* __restrict__ bo1,
    const float* __restrict__ Wo2, const float* __restrict__ bo2,
    const float* __restrict__ S, const float* __restrict__ W3,
    const float* __restrict__ c3, const float* __restrict__ cnt,
    float* __restrict__ out)
{
    __shared__ __align__(16) float sS[KK][ATP];
    __shared__ __align__(16) float tb[HH][ATP];
    __shared__ __align__(16) float sX[FF][ATP];
    __shared__ float pr[4][8];
    __shared__ float po[AT];
    __shared__ float svalid[AT];

    const int tid = threadIdx.x;
    const int hh  = tid & 127;
    const int sh  = tid >> 7;            // atom half: atoms sh*8 .. sh*8+7
    const int a0  = blockIdx.x * AT;     // 96 % 16 == 0 -> block within one molecule
    const int b   = a0 / NN;
    const float cb = cnt[b];

    // ---- stage S^T, X^T, validity ----
    {
        int k = tid & 63, al = tid >> 6;
        #pragma unroll
        for (int r = 0; r < AT / 4; ++r)
            sS[k][al + r * 4] = S[(a0 + al + r * 4) * KK + k];
    }
    {
        int f = tid & 15, al = tid >> 4;  // 256 = 16*16 exactly
        sX[f][al] = X[(a0 + al) * FF + f];
    }
    if (tid < AT) svalid[tid] = (batch[a0 + tid] != -1) ? 1.f : 0.f;
    __syncthreads();

    // ---- embedding: h = X@We + be ----
    float h[8];
    {
        float acc[8] = {0, 0, 0, 0, 0, 0, 0, 0};
        const float* wp = We + hh;
        #pragma unroll
        for (int f = 0; f < FF; ++f) {
            float w = wp[f * HH];
            FMA8(acc, w, sX[f]);
        }
        float bee = be[hh];
        #pragma unroll
        for (int a = 0; a < 8; ++a) h[a] = acc[a] + bee;
    }

    // ---- layers ----
    for (int l = 0; l < LL; ++l) {
        // ---- a1 = S@W3 (pipelined over k) ----
        float acc[8] = {0, 0, 0, 0, 0, 0, 0, 0};
        {
            const float* wp = W3 + l * KK * HH + hh;
            float wreg[8];
            #pragma unroll
            for (int kk = 0; kk < 8; ++kk) wreg[kk] = wp[kk * HH];
            for (int kb = 0; kb < KK; kb += 8) {
                float wnext[8];
                const bool more = (kb + 8 < KK);
                #pragma unroll
                for (int kk = 0; kk < 8; ++kk)
                    wnext[kk] = more ? wp[(kb + 8 + kk) * HH] : 0.f;
                #pragma unroll
                for (int kk = 0; kk < 8; ++kk) FMA8(acc, wreg[kk], sS[kb + kk]);
                #pragma unroll
                for (int kk = 0; kk < 8; ++kk) wreg[kk] = wnext[kk];
            }
        }
        float bias = cb * c3[l * HH + hh] + ba1[l * HH + hh];

        __syncthreads();   // previous consumers of tb done
        {
            float4 t0, t1; float v;
            v = acc[0] + bias; t0.x = v / (1.f + __expf(-v));
            v = acc[1] + bias; t0.y = v / (1.f + __expf(-v));
            v = acc[2] + bias; t0.z = v / (1.f + __expf(-v));
            v = acc[3] + bias; t0.w = v / (1.f + __expf(-v));
            v = acc[4] + bias; t1.x = v / (1.f + __expf(-v));
            v = acc[5] + bias; t1.y = v / (1.f + __expf(-v));
            v = acc[6] + bias; t1.z = v / (1.f + __expf(-v));
            v = acc[7] + bias; t1.w = v / (1.f + __expf(-v));
            *(float4*)&tb[hh][sh * 8]     = t0;
            *(float4*)&tb[hh][sh * 8 + 4] = t1;
        }
        __syncthreads();

        // ---- h += t@Wa2 (pipelined over m) ----
        float acc2[8] = {0, 0, 0, 0, 0, 0, 0, 0};
        {
            const float* wq = Wa2 + l * HH * HH + hh;
            float wreg[8];
            #pragma unroll
            for (int kk = 0; kk < 8; ++kk) wreg[kk] = wq[kk * HH];
            for (int mb = 0; mb < HH; mb += 8) {
                float wnext[8];
                const bool more = (mb + 8 < HH);
                #pragma unroll
                for (int kk = 0; kk < 8; ++kk)
                    wnext[kk] = more ? wq[(mb + 8 + kk) * HH] : 0.f;
                #pragma unroll
                for (int kk = 0; kk < 8; ++kk) FMA8(acc2, wreg[kk], tb[mb + kk]);
                #pragma unroll
                for (int kk = 0; kk < 8; ++kk) wreg[kk] = wnext[kk];
            }
        }
        float b2 = ba2[l * HH + hh];
        #pragma unroll
        for (int a = 0; a < 8; ++a) h[a] += acc2[a] + b2;
    }

    // ---- output head ----
    __syncthreads();
    *(float4*)&tb[hh][sh * 8]     = make_float4(h[0], h[1], h[2], h[3]);
    *(float4*)&tb[hh][sh * 8 + 4] = make_float4(h[4], h[5], h[6], h[7]);
    __syncthreads();

    float acc[8] = {0, 0, 0, 0, 0, 0, 0, 0};
    {
        const float* wp = Wo1 + hh;
        float wreg[8];
        #pragma unroll
        for (int kk = 0; kk < 8; ++kk) wreg[kk] = wp[kk * HH];
        for (int mb = 0; mb < HH; mb += 8) {
            float wnext[8];
            const bool more = (mb + 8 < HH);
            #pragma unroll
            for (int kk = 0; kk < 8; ++kk)
                wnext[kk] = more ? wp[(mb + 8 + kk) * HH] : 0.f;
            #pragma unroll
            for (int kk = 0; kk < 8; ++kk) FMA8(acc, wreg[kk], tb[mb + kk]);
            #pragma unroll
            for (int kk = 0; kk < 8; ++kk) wreg[kk] = wnext[kk];
        }
    }
    float bo = bo1[hh], wo2 = Wo2[hh];
    float contrib[8];
    #pragma unroll
    for (int a = 0; a < 8; ++a) {
        float v = acc[a] + bo;
        contrib[a] = (v / (1.f + __expf(-v))) * wo2;
    }
    #pragma unroll
    for (int a = 0; a < 8; ++a) {
        float r = contrib[a];
        for (int off = 32; off > 0; off >>= 1) r += __shfl_down(r, off);
        contrib[a] = r;
    }
    if ((tid & 63) == 0) {
        int w = tid >> 6;
        #pragma unroll
        for (int a = 0; a < 8; ++a) pr[w][a] = contrib[a];
    }
    __syncthreads();
    if (tid < AT) {
        int shh = tid >> 3, ai = tid & 7;
        float o = pr[2 * shh][ai] + pr[2 * shh + 1][ai] + bo2[0];
        po[tid] = (svalid[tid] != 0.f) ? o : 0.f;   // select: kills any NaN path
    }
    __syncthreads();
    if (tid == 0) {
        float s = 0.f;
        #pragma unroll
        for (int i = 0; i < AT; ++i) s += po[i];
        atomicAdd(out + b, s / cb);
    }
}

extern "C" void kernel_launch(void* const* d_in, const int* in_sizes, int n_in,
                              void* d_out, int out_size, void* d_ws, size_t ws_size,
                              hipStream_t stream) {
    const float* X     = (const float*)d_in[0];
    const float* R     = (const float*)d_in[1];
    const int*   batch = (const int*)  d_in[2];
    const float* We    = (const float*)d_in[3];
    const float* be    = (const float*)d_in[4];
    const float* Wrbf  = (const float*)d_in[5];
    const float* brbf  = (const float*)d_in[6];
    const float* Wpair = (const float*)d_in[7];
    const float* bpair = (const float*)d_in[8];
    const float* Wa1   = (const float*)d_in[9];
    const float* ba1   = (const float*)d_in[10];
    const float* Wa2   = (const float*)d_in[11];
    const float* ba2   = (const float*)d_in[12];
    const float* Wo1   = (const float*)d_in[13];
    const float* bo1   = (const float*)d_in[14];
    const float* Wo2   = (const float*)d_in[15];
    const float* bo2   = (const float*)d_in[16];

    float* w   = (float*)d_ws;
    float* S   = w;                        // B*N*K = 393216
    float* W3  = S  + BB * NN * KK;        // L*K*H = 24576
    float* c3  = W3 + LL * KK * HH;        // L*H   = 384
    float* cnt = c3 + LL * HH;             // B     = 64
    float* out = (float*)d_out;

    hipLaunchKernelGGL(pre_kernel, dim3(WT_BLOCKS + CNT_BLOCKS + S_BLOCKS), dim3(256),
                       0, stream, Wrbf, brbf, Wpair, bpair, Wa1, batch, R,
                       W3, c3, cnt, S, out);
    hipLaunchKernelGGL(chain_kernel, dim3(BB * NN / AT), dim3(256), 0, stream,
                       X, batch, We, be, ba1, Wa2, ba2, Wo1, bo1, Wo2, bo2,
                       S, W3, c3, cnt, out);
}

// Round 6
// 56.199 us; speedup vs baseline: 2.1267x; 1.1850x over previous
//
#include <hip/hip_runtime.h>
#include <hip/hip_bf16.h>

#define BB 64
#define NN 96
#define FF 16
#define HH 128
#define KK 64
#define LL 3
#define CUTOFF_F 10.0f
#define GAMMA_F 10.0f

#define WT_BLOCKS 99          // 3 layers * 33 blocks (2 rows of W3 each, 65 rows/layer)
#define CNT_BLOCKS BB

// ---------------------------------------------------------------------------
// pre_kernel:
//   [0,99):   rows {2i,2i+1} of W2[l]=Wrbf@Wpair (row 64 = bias row) staged in
//             LDS, then W3 rows = W2row@Wa1 (row 64 -> c3).
//   [99,163): cnt[b] = #valid atoms; zero out[b] (atomic target in chain)
// ---------------------------------------------------------------------------
__global__ __launch_bounds__(256) void pre_kernel(
    const float* __restrict__ Wrbf, const float* __restrict__ brbf,
    const float* __restrict__ Wpair, const float* __restrict__ bpair,
    const float* __restrict__ Wa1,
    const int* __restrict__ batch,
    float* __restrict__ W3, float* __restrict__ c3,
    float* __restrict__ cnt, float* __restrict__ out)
{
    const int bid = blockIdx.x;
    const int tid = threadIdx.x;
    if (bid < WT_BLOCKS) {
        __shared__ float sW2[2][HH];
        const int l    = bid / 33;
        const int r0   = (bid % 33) * 2;
        const int half = tid >> 7;
        const int h    = tid & 127;
        const int kk   = r0 + half;       // 0..65 (65 inactive)
        const bool active = (kk <= KK);
        if (active) {
            const float* Wp = Wpair + l * HH * HH + h;
            const float* arow;
            float acc;
            if (kk < KK) { arow = Wrbf + (l * KK + kk) * HH; acc = 0.f; }
            else         { arow = brbf + l * HH;             acc = bpair[l * HH + h]; }
            #pragma unroll 8
            for (int m = 0; m < HH; ++m) acc += arow[m] * Wp[m * HH];
            sW2[half][h] = acc;
        }
        __syncthreads();
        if (active) {
            const float* Wa = Wa1 + l * HH * HH + h;
            const float* row = sW2[half];
            float a3 = 0.f;
            #pragma unroll 8
            for (int m = 0; m < HH; ++m) a3 += row[m] * Wa[m * HH];
            if (kk < KK) W3[(l * KK + kk) * HH + h] = a3;
            else         c3[l * HH + h] = a3;
        }
    } else {
        int b = bid - WT_BLOCKS;
        __shared__ int c[4];
        bool v = (tid < NN) && (batch[b * NN + tid] != -1);
        unsigned long long m = __ballot(v);
        if ((tid & 63) == 0) c[tid >> 6] = __popcll(m);
        __syncthreads();
        if (tid == 0) {
            cnt[b] = (float)(c[0] + c[1] + c[2] + c[3]);
            out[b] = 0.f;                 // zero the atomic target each call
        }
    }
}

// ---------------------------------------------------------------------------
// chain_kernel: fused S-compute + per-atom MLP chain.
// Block = 256 threads = 128 channels x 2 atom-halves of 6 atoms (AT=12).
// Weights streamed into LDS (2 x 32KB ping-pong) via global_load_lds DMA,
// one chunk in flight hidden under each GEMM.
// ---------------------------------------------------------------------------
#define AT 12
#define COLW 16   // atom-slot row width; halves at cols 0..5 and 8..13

typedef const __attribute__((address_space(1))) void* gp1_t;
typedef __attribute__((address_space(3))) void* lp3_t;

// DMA one 32KB chunk (8192 floats) global -> LDS, whole block cooperating.
__device__ __forceinline__ void stage32k(const float* g, float* l, int tid)
{
    const int lane = tid & 63, wv = tid >> 6;
    #pragma unroll
    for (int j = 0; j < 8; ++j) {
        const int base = j * 256 + wv * 64;            // float4 units
        __builtin_amdgcn_global_load_lds((gp1_t)(g + (size_t)(base + lane) * 4),
                                         (lp3_t)(l + (size_t)base * 4), 16, 0, 0);
    }
}

#define VMCNT0() asm volatile("s_waitcnt vmcnt(0)" ::: "memory")

#define FMA6(ACC, W, ROWPTR)                                        \
    do {                                                            \
        float4 _u0 = *(const float4*)&(ROWPTR)[sh8];                \
        float2 _u1 = *(const float2*)&(ROWPTR)[sh8 + 4];            \
        ACC[0] += (W) * _u0.x; ACC[1] += (W) * _u0.y;               \
        ACC[2] += (W) * _u0.z; ACC[3] += (W) * _u0.w;               \
        ACC[4] += (W) * _u1.x; ACC[5] += (W) * _u1.y;               \
    } while (0)

__global__ __launch_bounds__(256) void chain_kernel(
    const float* __restrict__ X, const float* __restrict__ R,
    const float* __restrict__ We, const float* __restrict__ be,
    const float* __restrict__ ba1, const float* __restrict__ Wa2,
    const float* __restrict__ ba2, const float* __restrict__ Wo1,
    const float* __restrict__ bo1, const float* __restrict__ Wo2,
    const float* __restrict__ bo2, const float* __restrict__ W3,
    const float* __restrict__ c3, const float* __restrict__ cnt,
    float* __restrict__ out)
{
    __shared__ __align__(16) float sS[KK][COLW];     // 4 KB  (S^T, persists)
    __shared__ __align__(16) float tb[HH][COLW];     // 8 KB  (t / h staging; aliased early)
    __shared__ __align__(16) float sX[FF][COLW];     // 1 KB
    __shared__ __align__(16) float wb[2][KK * HH];   // 64 KB weight ping-pong
    __shared__ float pr[4][6];
    __shared__ float po[AT];
    __shared__ float svalid[AT];

    const int tid = threadIdx.x;
    const int hh  = tid & 127;
    const int sh  = tid >> 7;
    const int sh8 = sh * 8;
    const int a0  = blockIdx.x * AT;     // 96 % 12 == 0 -> block within one molecule
    const int b   = a0 / NN;
    const int lbase = a0 - b * NN;       // molecule-local first atom
    const float cb = cnt[b];
    const int nv  = (int)cb;             // valid atoms are prefix 0..nv-1 (molecule-local)

    // scratch aliased into tb (dead before first tb write)
    float* sRf = &tb[0][0];              // 288 floats: molecule R
    float* sD  = sRf + 384;              // 12*96 distances

    // ---- issue weight DMAs for layer 0 ----
    stage32k(W3, wb[0], tid);            // W3[0]
    stage32k(Wa2, wb[1], tid);           // Wa2[0] rows 0..63

    // ---- stage molecule R, X^T, validity ----
    for (int t = tid; t < NN * 3; t += 256) sRf[t] = R[b * NN * 3 + t];
    if (tid < AT * FF) {
        int a = tid >> 4, f = tid & 15;
        int col = (a < 6) ? a : a + 2;
        sX[f][col] = X[(a0 + a) * FF + f];
    }
    if (tid < AT) svalid[tid] = (lbase + tid < nv) ? 1.f : 0.f;
    __syncthreads();

    // ---- phase 1: distance table D[j][i] (j block-local) ----
    for (int e = tid; e < AT * NN; e += 256) {
        int j = e / NN, i = e - j * NN;
        float dx = sRf[i * 3 + 0] - sRf[(lbase + j) * 3 + 0];
        float dy = sRf[i * 3 + 1] - sRf[(lbase + j) * 3 + 1];
        float dz = sRf[i * 3 + 2] - sRf[(lbase + j) * 3 + 2];
        sD[e] = sqrtf(dx * dx + dy * dy + dz * dz);
    }
    __syncthreads();

    // ---- phase 2: sS[k][col(j)] = sum_{i<nv} exp(-g*(D[j][i]-ck)^2) ----
    {
        const int k  = tid & 63;
        const int wv = tid >> 6;
        const float ck = (float)k * (CUTOFF_F / (float)(KK - 1));
        #pragma unroll
        for (int r = 0; r < 3; ++r) {
            int j = wv * 3 + r;
            int col = (j < 6) ? j : j + 2;
            if (lbase + j >= nv) { sS[k][col] = 0.f; continue; }
            const float* Dr = sD + j * NN;
            float acc = 0.f;
            for (int i = 0; i < nv; ++i) {
                float u = Dr[i] - ck;
                acc += __expf(-GAMMA_F * u * u);
            }
            sS[k][col] = acc;
        }
    }

    // ---- embedding: h = X@We + be (global We; hides DMA) ----
    float h[6];
    {
        float acc[6] = {0, 0, 0, 0, 0, 0};
        const float* wp = We + hh;
        #pragma unroll
        for (int f = 0; f < FF; ++f) { float w = wp[f * HH]; FMA6(acc, w, sX[f]); }
        float bee = be[hh];
        #pragma unroll
        for (int a = 0; a < 6; ++a) h[a] = acc[a] + bee;
    }

    VMCNT0();
    __syncthreads();   // sync0: wb[0]=W3[0], wb[1]=Wa2[0]a ready; sS visible; sD dead

    // ---- layers ----
    for (int l = 0; l < LL; ++l) {
        const int P = l & 1, Q = P ^ 1;

        // GEMM1: acc = S @ W3[l]   (reads wb[P], sS)
        float acc[6] = {0, 0, 0, 0, 0, 0};
        {
            const float* wp = &wb[P][hh];
            #pragma unroll 8
            for (int k = 0; k < KK; ++k) { float w = wp[k * HH]; FMA6(acc, w, sS[k]); }
        }
        float bias = cb * c3[l * HH + hh] + ba1[l * HH + hh];
        // silu -> tb  (tb writable since last barrier; not read by GEMM1)
        {
            float4 t0; float2 t1; float v;
            v = acc[0] + bias; t0.x = v / (1.f + __expf(-v));
            v = acc[1] + bias; t0.y = v / (1.f + __expf(-v));
            v = acc[2] + bias; t0.z = v / (1.f + __expf(-v));
            v = acc[3] + bias; t0.w = v / (1.f + __expf(-v));
            v = acc[4] + bias; t1.x = v / (1.f + __expf(-v));
            v = acc[5] + bias; t1.y = v / (1.f + __expf(-v));
            *(float4*)&tb[hh][sh8]     = t0;
            *(float2*)&tb[hh][sh8 + 4] = t1;
        }
        VMCNT0();
        __syncthreads();   // sync1: wb[P] free, tb visible, wb[Q] (Wa2a) ready
        stage32k(Wa2 + l * HH * HH + 64 * HH, wb[P], tid);   // Wa2[l] rows 64..127

        // GEMM2a: m = 0..63 from wb[Q]
        float acc2[6] = {0, 0, 0, 0, 0, 0};
        {
            const float* wq = &wb[Q][hh];
            #pragma unroll 8
            for (int m = 0; m < 64; ++m) { float w = wq[m * HH]; FMA6(acc2, w, tb[m]); }
        }
        VMCNT0();
        __syncthreads();   // sync2: wb[Q] free, wb[P] (Wa2b) ready
        stage32k((l < LL - 1) ? (W3 + (l + 1) * KK * HH) : Wo1, wb[Q], tid);

        // GEMM2b: m = 64..127 from wb[P]
        {
            const float* wp = &wb[P][hh];
            #pragma unroll 8
            for (int m = 0; m < 64; ++m) { float w = wp[m * HH]; FMA6(acc2, w, tb[m + 64]); }
        }
        float b2 = ba2[l * HH + hh];
        #pragma unroll
        for (int a = 0; a < 6; ++a) h[a] += acc2[a] + b2;
        VMCNT0();
        __syncthreads();   // sync3: wb[P] free, wb[Q] (next W3 / Wo1a) ready, tb free
        stage32k((l < LL - 1) ? (Wa2 + (l + 1) * HH * HH) : (Wo1 + 64 * HH), wb[P], tid);
    }
    // after loop (LL=3 odd): wb[1] = Wo1 rows 0..63, wb[0] = Wo1 rows 64..127

    // ---- output head ----
    *(float4*)&tb[hh][sh8]     = make_float4(h[0], h[1], h[2], h[3]);
    *(float2*)&tb[hh][sh8 + 4] = make_float2(h[4], h[5]);
    VMCNT0();
    __syncthreads();   // sync4: tb visible, both Wo1 chunks ready

    float acc[6] = {0, 0, 0, 0, 0, 0};
    {
        const float* wq = &wb[1][hh];
        #pragma unroll 8
        for (int m = 0; m < 64; ++m) { float w = wq[m * HH]; FMA6(acc, w, tb[m]); }
        const float* wp = &wb[0][hh];
        #pragma unroll 8
        for (int m = 0; m < 64; ++m) { float w = wp[m * HH]; FMA6(acc, w, tb[m + 64]); }
    }
    float bo = bo1[hh], wo2 = Wo2[hh];
    float contrib[6];
    #pragma unroll
    for (int a = 0; a < 6; ++a) {
        float v = acc[a] + bo;
        contrib[a] = (v / (1.f + __expf(-v))) * wo2;
    }
    #pragma unroll
    for (int a = 0; a < 6; ++a) {
        float r = contrib[a];
        for (int off = 32; off > 0; off >>= 1) r += __shfl_down(r, off);
        contrib[a] = r;
    }
    if ((tid & 63) == 0) {
        int w = tid >> 6;
        #pragma unroll
        for (int a = 0; a < 6; ++a) pr[w][a] = contrib[a];
    }
    __syncthreads();
    if (tid < AT) {
        int half = tid / 6, ai = tid % 6;
        float o = pr[half * 2][ai] + pr[half * 2 + 1][ai] + bo2[0];
        po[tid] = (svalid[tid] != 0.f) ? o : 0.f;
    }
    __syncthreads();
    if (tid == 0) {
        float s = 0.f;
        #pragma unroll
        for (int i = 0; i < AT; ++i) s += po[i];
        atomicAdd(out + b, s / cb);
    }
}

extern "C" void kernel_launch(void* const* d_in, const int* in_sizes, int n_in,
                              void* d_out, int out_size, void* d_ws, size_t ws_size,
                              hipStream_t stream) {
    const float* X     = (const float*)d_in[0];
    const float* R     = (const float*)d_in[1];
    const int*   batch = (const int*)  d_in[2];
    const float* We    = (const float*)d_in[3];
    const float* be    = (const float*)d_in[4];
    const float* Wrbf  = (const float*)d_in[5];
    const float* brbf  = (const float*)d_in[6];
    const float* Wpair = (const float*)d_in[7];
    const float* bpair = (const float*)d_in[8];
    const float* Wa1   = (const float*)d_in[9];
    const float* ba1   = (const float*)d_in[10];
    const float* Wa2   = (const float*)d_in[11];
    const float* ba2   = (const float*)d_in[12];
    const float* Wo1   = (const float*)d_in[13];
    const float* bo1   = (const float*)d_in[14];
    const float* Wo2   = (const float*)d_in[15];
    const float* bo2   = (const float*)d_in[16];

    float* w   = (float*)d_ws;
    float* W3  = w;                        // L*K*H = 24576
    float* c3  = W3 + LL * KK * HH;        // L*H   = 384
    float* cnt = c3 + LL * HH;             // B     = 64
    float* out = (float*)d_out;

    hipLaunchKernelGGL(pre_kernel, dim3(WT_BLOCKS + CNT_BLOCKS), dim3(256),
                       0, stream, Wrbf, brbf, Wpair, bpair, Wa1, batch,
                       W3, c3, cnt, out);
    hipLaunchKernelGGL(chain_kernel, dim3(BB * NN / AT), dim3(256), 0, stream,
                       X, R, We, be, ba1, Wa2, ba2, Wo1, bo1, Wo2, bo2,
                       W3, c3, cnt, out);
}